// Round 1
// baseline (6239.055 us; speedup 1.0000x reference)
//
#include <hip/hip_runtime.h>
#include <cstdint>

// Problem dims
constexpr int Bb  = 2, Ss = 1024, Dd = 2048, Hh = 16, DHh = 128;
constexpr int Ee  = 8, HIDc = 4096;
constexpr int Tt  = Bb * Ss;            // 2048 tokens
constexpr int ARENA = Tt * 2 + 128;     // 4224 rows (top-2 assignments + tile slack)

typedef float    f32x4 __attribute__((ext_vector_type(4)));
typedef _Float16 f16x8 __attribute__((ext_vector_type(8)));

// ---------- helpers ----------
__device__ __forceinline__ f16x8 cvt8(const float* p) {
  const float4* q = reinterpret_cast<const float4*>(p);
  float4 a = q[0], b = q[1];
  f16x8 r;
  r[0] = (_Float16)a.x; r[1] = (_Float16)a.y; r[2] = (_Float16)a.z; r[3] = (_Float16)a.w;
  r[4] = (_Float16)b.x; r[5] = (_Float16)b.y; r[6] = (_Float16)b.z; r[7] = (_Float16)b.w;
  return r;
}

// 64x64 wave tile, split-fp16 3-product GEMM loop (error ~2^-21 relative).
// aH/aL/wH/wL already offset to (tile_row + lane&15)*K + (lane>>4)*8.
__device__ __forceinline__ void mm_split(const _Float16* aH, const _Float16* aL,
                                         const _Float16* wH, const _Float16* wL,
                                         int K, f32x4 (&acc)[4][4]) {
  for (int k = 0; k < K; k += 32) {
    f16x8 ah[4], al[4], bh[4], bl[4];
#pragma unroll
    for (int i = 0; i < 4; i++) {
      size_t o = (size_t)(i * 16) * K + k;
      ah[i] = *(const f16x8*)(aH + o);
      al[i] = *(const f16x8*)(aL + o);
      bh[i] = *(const f16x8*)(wH + o);
      bl[i] = *(const f16x8*)(wL + o);
    }
#pragma unroll
    for (int mi = 0; mi < 4; mi++)
#pragma unroll
      for (int ni = 0; ni < 4; ni++) {
        f32x4 c = acc[mi][ni];
        c = __builtin_amdgcn_mfma_f32_16x16x32_f16(ah[mi], bh[ni], c, 0, 0, 0);
        c = __builtin_amdgcn_mfma_f32_16x16x32_f16(ah[mi], bl[ni], c, 0, 0, 0);
        c = __builtin_amdgcn_mfma_f32_16x16x32_f16(al[mi], bh[ni], c, 0, 0, 0);
        acc[mi][ni] = c;
      }
  }
}

// ---------- kernels ----------
// RMSNorm -> split fp16 planes (high + low residual)
__global__ __launch_bounds__(256) void rms_split_kernel(const float* __restrict__ x,
    const float* __restrict__ w, _Float16* __restrict__ oh, _Float16* __restrict__ ol) {
  int t = blockIdx.x, tid = threadIdx.x;
  const float* row = x + (size_t)t * Dd;
  float ss = 0.f;
  for (int d = tid; d < Dd; d += 256) { float v = row[d]; ss += v * v; }
  __shared__ float red[256];
  red[tid] = ss; __syncthreads();
  for (int st = 128; st > 0; st >>= 1) { if (tid < st) red[tid] += red[tid + st]; __syncthreads(); }
  float rinv = 1.0f / sqrtf(red[0] * (1.0f / Dd) + 1e-8f);
  for (int d = tid; d < Dd; d += 256) {
    float v = row[d] * rinv * w[d];
    _Float16 hh = (_Float16)v;
    oh[(size_t)t * Dd + d] = hh;
    ol[(size_t)t * Dd + d] = (_Float16)(v - (float)hh);
  }
}

// RMSNorm -> single fp16 plane (MoE input)
__global__ __launch_bounds__(256) void rms_plain_kernel(const float* __restrict__ x,
    const float* __restrict__ w, _Float16* __restrict__ o) {
  int t = blockIdx.x, tid = threadIdx.x;
  const float* row = x + (size_t)t * Dd;
  float ss = 0.f;
  for (int d = tid; d < Dd; d += 256) { float v = row[d]; ss += v * v; }
  __shared__ float red[256];
  red[tid] = ss; __syncthreads();
  for (int st = 128; st > 0; st >>= 1) { if (tid < st) red[tid] += red[tid + st]; __syncthreads(); }
  float rinv = 1.0f / sqrtf(red[0] * (1.0f / Dd) + 1e-8f);
  for (int d = tid; d < Dd; d += 256)
    o[(size_t)t * Dd + d] = (_Float16)(row[d] * rinv * w[d]);
}

// split fp32 attention weights (wq,wk,wv,wo) into fp16 hi/lo planes
__global__ void wsplit_kernel(const float* w0, const float* w1, const float* w2, const float* w3,
    _Float16* h0, _Float16* l0, _Float16* h1, _Float16* l1,
    _Float16* h2, _Float16* l2, _Float16* h3, _Float16* l3) {
  int z = blockIdx.y;
  const float* w = (z == 0) ? w0 : (z == 1) ? w1 : (z == 2) ? w2 : w3;
  _Float16* hp = (z == 0) ? h0 : (z == 1) ? h1 : (z == 2) ? h2 : h3;
  _Float16* lp = (z == 0) ? l0 : (z == 1) ? l1 : (z == 2) ? l2 : l3;
  size_t i = (size_t)blockIdx.x * 256 + threadIdx.x;
  float f = w[i];
  _Float16 hh = (_Float16)f;
  hp[i] = hh;
  lp[i] = (_Float16)(f - (float)hh);
}

// QKV projection: q/k/v[t,o] = xn @ W^T + b   (split precision, fp32 out)
__global__ __launch_bounds__(256) void qkv_kernel(
    const _Float16* __restrict__ xh, const _Float16* __restrict__ xl,
    const _Float16* wqh, const _Float16* wql, const _Float16* wkh, const _Float16* wkl,
    const _Float16* wvh, const _Float16* wvl,
    const float* bq, const float* bk, const float* bv,
    float* oq, float* ok, float* ov) {
  int z = blockIdx.z;
  const _Float16* wH = (z == 0) ? wqh : (z == 1) ? wkh : wvh;
  const _Float16* wL = (z == 0) ? wql : (z == 1) ? wkl : wvl;
  const float* bias  = (z == 0) ? bq  : (z == 1) ? bk  : bv;
  float* O           = (z == 0) ? oq  : (z == 1) ? ok  : ov;
  int tid = threadIdx.x, lane = tid & 63, wid = tid >> 6;
  int m0 = blockIdx.x * 128 + (wid >> 1) * 64;
  int n0 = blockIdx.y * 128 + (wid & 1) * 64;
  int r = lane & 15, qd = lane >> 4;
  f32x4 acc[4][4];
  f32x4 zero4 = {0.f, 0.f, 0.f, 0.f};
#pragma unroll
  for (int i = 0; i < 4; i++)
#pragma unroll
    for (int j = 0; j < 4; j++) acc[i][j] = zero4;
  mm_split(xh + (size_t)(m0 + r) * Dd + qd * 8, xl + (size_t)(m0 + r) * Dd + qd * 8,
           wH + (size_t)(n0 + r) * Dd + qd * 8, wL + (size_t)(n0 + r) * Dd + qd * 8, Dd, acc);
#pragma unroll
  for (int mi = 0; mi < 4; mi++)
#pragma unroll
    for (int ni = 0; ni < 4; ni++) {
      int col = n0 + ni * 16 + r;
      float bb = bias[col];
#pragma unroll
      for (int g = 0; g < 4; g++) {
        int row = m0 + mi * 16 + qd * 4 + g;
        O[(size_t)row * Dd + col] = acc[mi][ni][g] + bb;
      }
    }
}

// RoPE (reference quirk: angle depends on HEAD index, not position), in-place on q,k
__global__ void rope_kernel(float* q, float* k) {
  int p = blockIdx.x * 256 + threadIdx.x;      // pair index, exactly Tt*Dd/2 threads
  int t = p >> 10;                              // Dd/2 = 1024 pairs per token
  int rem = p & 1023;
  int h = rem >> 6;                             // head 0..15
  int j = rem & 63;                             // freq 0..63
  float invf = exp2f(-(float)j * 0.20762050593045702f);  // 10000^(-j/64)
  float ang = (float)h * invf;
  float c = cosf(ang), sn = sinf(ang);
  size_t i0 = (size_t)t * Dd + h * DHh + 2 * j;
  float a1 = q[i0], a2 = q[i0 + 1];
  q[i0] = a1 * c - a2 * sn; q[i0 + 1] = a1 * sn + a2 * c;
  float b1 = k[i0], b2 = k[i0 + 1];
  k[i0] = b1 * c - b2 * sn; k[i0 + 1] = b1 * sn + b2 * c;
}

// causal attention, fp32, QT=4 query rows per block; writes split-fp16 o
constexpr int QT = 4;
__global__ __launch_bounds__(128) void attn_kernel(const float* __restrict__ qb,
    const float* __restrict__ kb, const float* __restrict__ vb,
    _Float16* __restrict__ ohp, _Float16* __restrict__ olp) {
  int tile = blockIdx.x;
  int bh = blockIdx.y; int b = bh >> 4, h = bh & 15;
  int tid = threadIdx.x;
  int s0 = tile * QT, smax = s0 + QT - 1;
  __shared__ alignas(16) float qs[QT][DHh];
  __shared__ float sc[QT][Ss];
  __shared__ float red[128];
  __shared__ float mrow[QT], lrow[QT];
  for (int i = tid; i < QT * DHh; i += 128) {
    int r = i >> 7, d = i & 127;
    qs[r][d] = qb[((size_t)(b * Ss + s0 + r)) * Dd + h * DHh + d] * 0.08838834764831845f;
  }
  __syncthreads();
  float tmax[QT], lsum[QT];
#pragma unroll
  for (int r = 0; r < QT; r++) { tmax[r] = -INFINITY; lsum[r] = 0.f; }
  for (int j = tid; j <= smax; j += 128) {
    const float4* kr = reinterpret_cast<const float4*>(kb + ((size_t)(b * Ss + j)) * Dd + h * DHh);
    float dot[QT];
#pragma unroll
    for (int r = 0; r < QT; r++) dot[r] = 0.f;
#pragma unroll 8
    for (int d4 = 0; d4 < DHh / 4; d4++) {
      float4 kv = kr[d4];
#pragma unroll
      for (int r = 0; r < QT; r++) {
        float4 qq = reinterpret_cast<const float4*>(qs[r])[d4];
        dot[r] += qq.x * kv.x + qq.y * kv.y + qq.z * kv.z + qq.w * kv.w;
      }
    }
#pragma unroll
    for (int r = 0; r < QT; r++)
      if (j <= s0 + r) { sc[r][j] = dot[r]; tmax[r] = fmaxf(tmax[r], dot[r]); }
  }
  for (int r = 0; r < QT; r++) {
    red[tid] = tmax[r]; __syncthreads();
    for (int st = 64; st > 0; st >>= 1) { if (tid < st) red[tid] = fmaxf(red[tid], red[tid + st]); __syncthreads(); }
    if (tid == 0) mrow[r] = red[0];
    __syncthreads();
  }
  for (int j = tid; j <= smax; j += 128) {
#pragma unroll
    for (int r = 0; r < QT; r++)
      if (j <= s0 + r) { float pe = expf(sc[r][j] - mrow[r]); sc[r][j] = pe; lsum[r] += pe; }
  }
  for (int r = 0; r < QT; r++) {
    red[tid] = lsum[r]; __syncthreads();
    for (int st = 64; st > 0; st >>= 1) { if (tid < st) red[tid] += red[tid + st]; __syncthreads(); }
    if (tid == 0) lrow[r] = 1.0f / red[0];
    __syncthreads();
  }
  float acc[QT];
#pragma unroll
  for (int r = 0; r < QT; r++) acc[r] = 0.f;
  int d = tid;  // 128 threads == DH
  for (int j = 0; j <= smax; j++) {
    float vv = vb[((size_t)(b * Ss + j)) * Dd + h * DHh + d];
#pragma unroll
    for (int r = 0; r < QT; r++)
      if (j <= s0 + r) acc[r] += sc[r][j] * vv;
  }
#pragma unroll
  for (int r = 0; r < QT; r++) {
    float oval = acc[r] * lrow[r];
    size_t idx = ((size_t)(b * Ss + s0 + r)) * Dd + h * DHh + d;
    _Float16 hh = (_Float16)oval;
    ohp[idx] = hh;
    olp[idx] = (_Float16)(oval - (float)hh);
  }
}

// O-projection + residual: out = x + o @ wo^T + bo   (split precision)
__global__ __launch_bounds__(256) void wo_kernel(
    const _Float16* __restrict__ ah, const _Float16* __restrict__ al,
    const _Float16* __restrict__ wH, const _Float16* __restrict__ wL,
    const float* __restrict__ bo, const float* __restrict__ resid, float* __restrict__ out) {
  int tid = threadIdx.x, lane = tid & 63, wid = tid >> 6;
  int m0 = blockIdx.x * 128 + (wid >> 1) * 64;
  int n0 = blockIdx.y * 128 + (wid & 1) * 64;
  int r = lane & 15, qd = lane >> 4;
  f32x4 acc[4][4];
  f32x4 zero4 = {0.f, 0.f, 0.f, 0.f};
#pragma unroll
  for (int i = 0; i < 4; i++)
#pragma unroll
    for (int j = 0; j < 4; j++) acc[i][j] = zero4;
  mm_split(ah + (size_t)(m0 + r) * Dd + qd * 8, al + (size_t)(m0 + r) * Dd + qd * 8,
           wH + (size_t)(n0 + r) * Dd + qd * 8, wL + (size_t)(n0 + r) * Dd + qd * 8, Dd, acc);
#pragma unroll
  for (int mi = 0; mi < 4; mi++)
#pragma unroll
    for (int ni = 0; ni < 4; ni++) {
      int col = n0 + ni * 16 + r;
      float bb = bo[col];
#pragma unroll
      for (int g = 0; g < 4; g++) {
        int row = m0 + mi * 16 + qd * 4 + g;
        out[(size_t)row * Dd + col] = acc[mi][ni][g] + bb + resid[(size_t)row * Dd + col];
      }
    }
}

__global__ void zero_kernel(int* cnt, int* cnt2) {
  if (threadIdx.x < Ee) { cnt[threadIdx.x] = 0; cnt2[threadIdx.x] = 0; }
}

// router: full fp32 logits from x2 (rmsnorm folded in), top-2 + 2-way softmax
__global__ __launch_bounds__(256) void router_kernel(const float* __restrict__ x2,
    const float* __restrict__ rmsw, const float* __restrict__ wr, const float* __restrict__ br,
    int* __restrict__ cnt, int* __restrict__ choice, float* __restrict__ cw) {
  int t = blockIdx.x, tid = threadIdx.x;
  const float* row = x2 + (size_t)t * Dd;
  float part[Ee];
#pragma unroll
  for (int e = 0; e < Ee; e++) part[e] = 0.f;
  float ss = 0.f;
  for (int d = tid; d < Dd; d += 256) {
    float xv = row[d];
    ss += xv * xv;
    float xw = xv * rmsw[d];
#pragma unroll
    for (int e = 0; e < Ee; e++) part[e] += xw * wr[e * Dd + d];
  }
  __shared__ float red[256];
  __shared__ float lg[Ee];
  __shared__ float rinv_s;
  red[tid] = ss; __syncthreads();
  for (int st = 128; st > 0; st >>= 1) { if (tid < st) red[tid] += red[tid + st]; __syncthreads(); }
  if (tid == 0) rinv_s = 1.0f / sqrtf(red[0] * (1.0f / Dd) + 1e-8f);
  __syncthreads();
  float rinv = rinv_s;
  for (int e = 0; e < Ee; e++) {
    red[tid] = part[e]; __syncthreads();
    for (int st = 128; st > 0; st >>= 1) { if (tid < st) red[tid] += red[tid + st]; __syncthreads(); }
    if (tid == 0) lg[e] = red[0] * rinv + br[e];
    __syncthreads();
  }
  if (tid == 0) {
    int i0 = 0; float v0 = lg[0];
    for (int e = 1; e < Ee; e++) if (lg[e] > v0) { v0 = lg[e]; i0 = e; }
    int i1 = -1; float v1 = -INFINITY;
    for (int e = 0; e < Ee; e++) if (e != i0 && lg[e] > v1) { v1 = lg[e]; i1 = e; }
    float ex = expf(v1 - v0);
    float w0 = 1.f / (1.f + ex), w1 = ex / (1.f + ex);
    choice[2 * t] = i0; choice[2 * t + 1] = i1;
    cw[2 * t] = w0; cw[2 * t + 1] = w1;
    atomicAdd(&cnt[i0], 1); atomicAdd(&cnt[i1], 1);
  }
}

__global__ void scan_kernel(const int* cnt, int* offs) {
  if (threadIdx.x == 0) {
    int a = 0;
    for (int e = 0; e < Ee; e++) { offs[e] = a; a += cnt[e]; }
  }
}

// gather token rows (fp16) into per-expert arena
__global__ __launch_bounds__(256) void gather_kernel(const _Float16* __restrict__ xn2,
    const int* __restrict__ choice, const float* __restrict__ cw,
    const int* __restrict__ offs, int* __restrict__ cnt2,
    _Float16* __restrict__ Xe, int* __restrict__ atok, float* __restrict__ awt) {
  int t = blockIdx.x, tid = threadIdx.x;
  __shared__ int rows[2];
  if (tid == 0) {
#pragma unroll
    for (int s = 0; s < 2; s++) {
      int e = choice[2 * t + s];
      int pos = atomicAdd(&cnt2[e], 1);
      int rw = offs[e] + pos;
      rows[s] = rw;
      atok[rw] = t; awt[rw] = cw[2 * t + s];
    }
  }
  __syncthreads();
  const uint4* src = reinterpret_cast<const uint4*>(xn2 + (size_t)t * Dd);
  uint4* d0 = reinterpret_cast<uint4*>(Xe + (size_t)rows[0] * Dd);
  uint4* d1 = reinterpret_cast<uint4*>(Xe + (size_t)rows[1] * Dd);
  uint4 val = src[tid];   // 256 threads * 16B = full 2048-elem fp16 row
  d0[tid] = val; d1[tid] = val;
}

// MoE GEMM1: a = silu(Xe @ Wg^T) * (Xe @ Wu^T), per expert, fp16 in/out fp32 acc
__global__ __launch_bounds__(256) void moe1_kernel(const _Float16* __restrict__ Xe,
    const float* __restrict__ Wg, const float* __restrict__ Wu,
    const int* __restrict__ cnt, const int* __restrict__ offs, _Float16* __restrict__ Aar) {
  int e = blockIdx.x >> 4, mb = blockIdx.x & 15;
  int ne = cnt[e];
  if (mb * 128 >= ne) return;
  int tid = threadIdx.x, lane = tid & 63, wid = tid >> 6;
  int mloc = mb * 128 + (wid >> 1) * 64;
  int n0 = blockIdx.y * 128 + (wid & 1) * 64;
  int r = lane & 15, qd = lane >> 4;
  int base = offs[e];
  const _Float16* aB = Xe + (size_t)(base + mloc + r) * Dd + qd * 8;
  const float* gB = Wg + (size_t)e * HIDc * Dd + (size_t)(n0 + r) * Dd + qd * 8;
  const float* uB = Wu + (size_t)e * HIDc * Dd + (size_t)(n0 + r) * Dd + qd * 8;
  f32x4 accg[4][4], accu[4][4];
  f32x4 zero4 = {0.f, 0.f, 0.f, 0.f};
#pragma unroll
  for (int i = 0; i < 4; i++)
#pragma unroll
    for (int j = 0; j < 4; j++) { accg[i][j] = zero4; accu[i][j] = zero4; }
  for (int k = 0; k < Dd; k += 32) {
    f16x8 af[4], bg[4], bu[4];
#pragma unroll
    for (int i = 0; i < 4; i++) {
      size_t o = (size_t)(i * 16) * Dd + k;
      af[i] = *(const f16x8*)(aB + o);
      bg[i] = cvt8(gB + o);
      bu[i] = cvt8(uB + o);
    }
#pragma unroll
    for (int mi = 0; mi < 4; mi++)
#pragma unroll
      for (int ni = 0; ni < 4; ni++) {
        accg[mi][ni] = __builtin_amdgcn_mfma_f32_16x16x32_f16(af[mi], bg[ni], accg[mi][ni], 0, 0, 0);
        accu[mi][ni] = __builtin_amdgcn_mfma_f32_16x16x32_f16(af[mi], bu[ni], accu[mi][ni], 0, 0, 0);
      }
  }
#pragma unroll
  for (int mi = 0; mi < 4; mi++)
#pragma unroll
    for (int ni = 0; ni < 4; ni++) {
      int col = n0 + ni * 16 + r;
#pragma unroll
      for (int g = 0; g < 4; g++) {
        int row_loc = mloc + mi * 16 + qd * 4 + g;
        if (row_loc < ne) {
          float gv = accg[mi][ni][g];
          float uv = accu[mi][ni][g];
          float aval = gv / (1.f + expf(-gv)) * uv;
          Aar[(size_t)(base + row_loc) * HIDc + col] = (_Float16)aval;
        }
      }
    }
}

// MoE GEMM2: out[t] += wt * (a @ Wd^T), scatter via atomicAdd
__global__ __launch_bounds__(256) void moe2_kernel(const _Float16* __restrict__ Aar,
    const float* __restrict__ Wd, const int* __restrict__ cnt, const int* __restrict__ offs,
    const int* __restrict__ atok, const float* __restrict__ awt, float* __restrict__ out) {
  int e = blockIdx.x >> 4, mb = blockIdx.x & 15;
  int ne = cnt[e];
  if (mb * 128 >= ne) return;
  int tid = threadIdx.x, lane = tid & 63, wid = tid >> 6;
  int mloc = mb * 128 + (wid >> 1) * 64;
  int n0 = blockIdx.y * 128 + (wid & 1) * 64;
  int r = lane & 15, qd = lane >> 4;
  int base = offs[e];
  const _Float16* aB = Aar + (size_t)(base + mloc + r) * HIDc + qd * 8;
  const float* wB = Wd + (size_t)e * Dd * HIDc + (size_t)(n0 + r) * HIDc + qd * 8;
  f32x4 acc[4][4];
  f32x4 zero4 = {0.f, 0.f, 0.f, 0.f};
#pragma unroll
  for (int i = 0; i < 4; i++)
#pragma unroll
    for (int j = 0; j < 4; j++) acc[i][j] = zero4;
  for (int k = 0; k < HIDc; k += 32) {
    f16x8 af[4], bw[4];
#pragma unroll
    for (int i = 0; i < 4; i++) {
      size_t o = (size_t)(i * 16) * HIDc + k;
      af[i] = *(const f16x8*)(aB + o);
      bw[i] = cvt8(wB + o);
    }
#pragma unroll
    for (int mi = 0; mi < 4; mi++)
#pragma unroll
      for (int ni = 0; ni < 4; ni++)
        acc[mi][ni] = __builtin_amdgcn_mfma_f32_16x16x32_f16(af[mi], bw[ni], acc[mi][ni], 0, 0, 0);
  }
#pragma unroll
  for (int mi = 0; mi < 4; mi++)
#pragma unroll
    for (int ni = 0; ni < 4; ni++) {
      int col = n0 + ni * 16 + r;
#pragma unroll
      for (int g = 0; g < 4; g++) {
        int row_loc = mloc + mi * 16 + qd * 4 + g;
        if (row_loc < ne) {
          int t = atok[base + row_loc];
          float w = awt[base + row_loc];
          atomicAdd(out + (size_t)t * Dd + col, acc[mi][ni][g] * w);
        }
      }
    }
}

// ---------- host ----------
extern "C" void kernel_launch(void* const* d_in, const int* in_sizes, int n_in,
                              void* d_out, int out_size, void* d_ws, size_t ws_size,
                              hipStream_t stream) {
  const float* x   = (const float*)d_in[0];
  const float* wq  = (const float*)d_in[1];
  const float* bq  = (const float*)d_in[2];
  const float* wk  = (const float*)d_in[3];
  const float* bk  = (const float*)d_in[4];
  const float* wv  = (const float*)d_in[5];
  const float* bv  = (const float*)d_in[6];
  const float* wo  = (const float*)d_in[7];
  const float* bo  = (const float*)d_in[8];
  const float* wr  = (const float*)d_in[9];
  const float* br  = (const float*)d_in[10];
  const float* wg  = (const float*)d_in[11];
  const float* wu  = (const float*)d_in[12];
  const float* wd  = (const float*)d_in[13];
  const float* r1w = (const float*)d_in[14];
  const float* r2w = (const float*)d_in[15];
  float* out = (float*)d_out;

  char* p = (char*)d_ws;
  auto alloc = [&](size_t n) { char* r = p; p += (n + 255) & ~(size_t)255; return (void*)r; };
  const size_t TD = (size_t)Tt * Dd;
  _Float16* xh  = (_Float16*)alloc(TD * 2);
  _Float16* xl  = (_Float16*)alloc(TD * 2);
  _Float16* wqh = (_Float16*)alloc((size_t)Dd * Dd * 2);
  _Float16* wql = (_Float16*)alloc((size_t)Dd * Dd * 2);
  _Float16* wkh = (_Float16*)alloc((size_t)Dd * Dd * 2);
  _Float16* wkl = (_Float16*)alloc((size_t)Dd * Dd * 2);
  _Float16* wvh = (_Float16*)alloc((size_t)Dd * Dd * 2);
  _Float16* wvl = (_Float16*)alloc((size_t)Dd * Dd * 2);
  _Float16* woh = (_Float16*)alloc((size_t)Dd * Dd * 2);
  _Float16* wol = (_Float16*)alloc((size_t)Dd * Dd * 2);
  float* qb = (float*)alloc(TD * 4);
  float* kb = (float*)alloc(TD * 4);
  float* vb = (float*)alloc(TD * 4);
  _Float16* ohp = (_Float16*)alloc(TD * 2);
  _Float16* olp = (_Float16*)alloc(TD * 2);
  _Float16* xn2 = (_Float16*)alloc(TD * 2);
  _Float16* Xe  = (_Float16*)alloc((size_t)ARENA * Dd * 2);
  _Float16* Aar = (_Float16*)alloc((size_t)ARENA * HIDc * 2);
  int*   cnt    = (int*)alloc(Ee * 4);
  int*   cnt2   = (int*)alloc(Ee * 4);
  int*   offs   = (int*)alloc(Ee * 4);
  int*   choice = (int*)alloc((size_t)Tt * 2 * 4);
  float* cw     = (float*)alloc((size_t)Tt * 2 * 4);
  int*   atok   = (int*)alloc((size_t)ARENA * 4);
  float* awt    = (float*)alloc((size_t)ARENA * 4);
  (void)ws_size; (void)in_sizes; (void)n_in; (void)out_size;

  // 1. RMSNorm1 -> split fp16
  rms_split_kernel<<<Tt, 256, 0, stream>>>(x, r1w, xh, xl);
  // 2. split attention weights
  wsplit_kernel<<<dim3((Dd * Dd) / 256, 4), 256, 0, stream>>>(
      wq, wk, wv, wo, wqh, wql, wkh, wkl, wvh, wvl, woh, wol);
  // 3. QKV projection
  qkv_kernel<<<dim3(Tt / 128, Dd / 128, 3), 256, 0, stream>>>(
      xh, xl, wqh, wql, wkh, wkl, wvh, wvl, bq, bk, bv, qb, kb, vb);
  // 4. RoPE in-place on q,k
  rope_kernel<<<(Tt * Dd / 2) / 256, 256, 0, stream>>>(qb, kb);
  // 5. causal attention -> split fp16 o
  attn_kernel<<<dim3(Ss / QT, Bb * Hh), 128, 0, stream>>>(qb, kb, vb, ohp, olp);
  // 6. o-proj + residual -> d_out (= x2)
  wo_kernel<<<dim3(Tt / 128, Dd / 128), 256, 0, stream>>>(ohp, olp, woh, wol, bo, x, out);
  // 7. RMSNorm2 -> fp16 (MoE input)
  rms_plain_kernel<<<Tt, 256, 0, stream>>>(out, r2w, xn2);
  // 8. routing
  zero_kernel<<<1, 64, 0, stream>>>(cnt, cnt2);
  router_kernel<<<Tt, 256, 0, stream>>>(out, r2w, wr, br, cnt, choice, cw);
  scan_kernel<<<1, 64, 0, stream>>>(cnt, offs);
  gather_kernel<<<Tt, 256, 0, stream>>>(xn2, choice, cw, offs, cnt2, Xe, atok, awt);
  // 9. MoE expert MLPs
  moe1_kernel<<<dim3(Ee * 16, HIDc / 128), 256, 0, stream>>>(Xe, wg, wu, cnt, offs, Aar);
  moe2_kernel<<<dim3(Ee * 16, Dd / 128), 256, 0, stream>>>(Aar, wd, cnt, offs, atok, awt, out);
}